// Round 10
// baseline (181.062 us; speedup 1.0000x reference)
//
#include <hip/hip_runtime.h>
#include <hip/hip_bf16.h>
#include <cstdint>

#define N_IDE 4096
#define M_U   16384
#define D_DIM 256
#define EPSF  1e-12f
#define INV_M (1.0f / 16384.0f)

#define CGC   512                 // columns per column-group tile
#define BK    32                  // K per step
#define SB_ELEMS (CGC * BK)       // 16384 f16 = 32 KB

typedef _Float16 f16x8 __attribute__((ext_vector_type(8)));
typedef float    f32x4 __attribute__((ext_vector_type(4)));
typedef short    short8 __attribute__((ext_vector_type(8)));

// ---- async global->LDS 16B copy. LDS dest = wave-uniform base + lane*16. ----
__device__ __forceinline__ void gll16(const void* g, void* l) {
  __builtin_amdgcn_global_load_lds(
      (const __attribute__((address_space(1))) void*)(uintptr_t)g,
      (__attribute__((address_space(3))) void*)(uint32_t)(uintptr_t)l,
      16, 0, 0);
}

__device__ __forceinline__ unsigned short f2h_bits(float f) {
  _Float16 h = (_Float16)f;
  return __builtin_bit_cast(unsigned short, h);
}

// ---- Kernel 1: fused conv + persistent-A MFMA GEMM (r7 loop verbatim) ----
// grid (8, 32), 512 threads. 3 kernels -> 2: the old k_conv is folded into
// the prologue. Per block:
//  (a) convert its 1/256 share of u (64 rows) fp32->f16 into Bh + y2 for
//      those rows; __threadfence + release-add a device counter.
//  (b) convert its OWN A tile (128 rows of ide) fp32->f16 straight into
//      swizzled LDS (Ah global round-trip deleted); x2 -> LDS sX.
//  (c) spin on cnt==256 (acquire, agent scope) -- safe: grid=256 blocks at
//      1 block/CU on 256 CUs => all co-resident; cnt memset each launch.
// Then the r7 51.7us K-loop runs unchanged (gll16 B staging from Bh f16).
__global__ __launch_bounds__(512, 2) void k_main(const float* __restrict__ ide,
                                                 const float* __restrict__ u,
                                                 unsigned short* __restrict__ Bh,
                                                 float* __restrict__ y2,
                                                 float* __restrict__ partial,
                                                 unsigned int* __restrict__ cnt,
                                                 float* __restrict__ out) {
  __shared__ __align__(16) unsigned short sA[128 * 256];      // 64 KB
  __shared__ __align__(16) unsigned short sB[2 * SB_ELEMS];   // 64 KB
  __shared__ float rowacc[4][128];                            // per-wn slices
  __shared__ float sX[128];                                   // block-local x2

  const int t    = threadIdx.x;
  const int w    = t >> 6;
  const int l    = t & 63;
  const int wm   = w >> 2, wn = w & 3;   // 2x4 wave grid; wave tile 64x128
  const int lrow = l & 15;
  const int lhi  = l >> 4;
  const int bx   = blockIdx.x;           // 0..7
  const int by   = blockIdx.y;           // 0..31
  const int blk  = by * 8 + bx;          // 0..255

  if (blk == 0 && t == 0) out[0] = 0.f;
  rowacc[t >> 7][t & 127] = 0.f;

  // ---- (a) B share: u rows [blk*64, +64) -> Bh f16 + y2 (fp32 norms) ----
  {
    const float* srcu = u + (size_t)blk * 64 * D_DIM;
    unsigned short* dstb = Bh + (size_t)blk * 64 * D_DIM;
#pragma unroll
    for (int it = 0; it < 4; ++it) {
      int c = it * 512 + t;              // chunk 0..2047 (8 f16 each)
      int row = c >> 5;                  // 0..63
      int p = c & 31;
      const float4* s4 = (const float4*)(srcu + (size_t)row * D_DIM + p * 8);
      float4 a = s4[0], b = s4[1];
      float sq = a.x*a.x + a.y*a.y + a.z*a.z + a.w*a.w
               + b.x*b.x + b.y*b.y + b.z*b.z + b.w*b.w;
      sq += __shfl_xor(sq, 1, 64);  sq += __shfl_xor(sq, 2, 64);
      sq += __shfl_xor(sq, 4, 64);  sq += __shfl_xor(sq, 8, 64);
      sq += __shfl_xor(sq, 16, 64);      // reduce within 32-lane row groups
      if ((l & 31) == 0) y2[blk * 64 + row] = sq;
      short8 o;
      o[0] = (short)f2h_bits(a.x); o[1] = (short)f2h_bits(a.y);
      o[2] = (short)f2h_bits(a.z); o[3] = (short)f2h_bits(a.w);
      o[4] = (short)f2h_bits(b.x); o[5] = (short)f2h_bits(b.y);
      o[6] = (short)f2h_bits(b.z); o[7] = (short)f2h_bits(b.w);
      *(short8*)(dstb + (size_t)row * D_DIM + p * 8) = o;
    }
  }
  __threadfence();                       // device-scope: publish Bh + y2
  __syncthreads();                       // all threads' stores fenced
  if (t == 0)
    __hip_atomic_fetch_add(cnt, 1u, __ATOMIC_RELEASE, __HIP_MEMORY_SCOPE_AGENT);

  // ---- (b) A tile: ide rows [by*128,+128) -> swizzled sA; x2 -> sX ----
  // LDS slot L holds global chunk swz(p) (matches r7's gll16 layout exactly).
  {
    const float* srca = ide + (size_t)by * 128 * D_DIM;
#pragma unroll
    for (int i = 0; i < 8; ++i) {
      int L = i * 512 + t;               // slot id 0..4095
      int row = L >> 5;                  // 0..127
      int p = L & 31;
      int c = (p & 24) | ((p & 7) ^ (row & 7));
      const float4* s4 = (const float4*)(srca + (size_t)row * D_DIM + c * 8);
      float4 a = s4[0], b = s4[1];
      float sq = a.x*a.x + a.y*a.y + a.z*a.z + a.w*a.w
               + b.x*b.x + b.y*b.y + b.z*b.z + b.w*b.w;
      sq += __shfl_xor(sq, 1, 64);  sq += __shfl_xor(sq, 2, 64);
      sq += __shfl_xor(sq, 4, 64);  sq += __shfl_xor(sq, 8, 64);
      sq += __shfl_xor(sq, 16, 64);
      if ((l & 31) == 0) sX[row] = sq;
      short8 o;
      o[0] = (short)f2h_bits(a.x); o[1] = (short)f2h_bits(a.y);
      o[2] = (short)f2h_bits(a.z); o[3] = (short)f2h_bits(a.w);
      o[4] = (short)f2h_bits(b.x); o[5] = (short)f2h_bits(b.y);
      o[6] = (short)f2h_bits(b.z); o[7] = (short)f2h_bits(b.w);
      *(short8*)(sA + (size_t)L * 8) = o;
    }
  }

  // ---- (c) wait for all 256 B shares (overlaps (b) work above) ----
  if (t == 0) {
    while (__hip_atomic_load(cnt, __ATOMIC_ACQUIRE, __HIP_MEMORY_SCOPE_AGENT) < 256u)
      __builtin_amdgcn_s_sleep(8);
  }
  __syncthreads();                       // sA/sX visible + Bh globally ready

  // ================= r7 K-loop, verbatim =================
  auto stageB = [&](int s) {
    const int cgi = (s >> 3) * 8 + bx;   // column-group 0..31
    const int kt  = s & 7;
    const unsigned short* src = Bh + (size_t)cgi * CGC * D_DIM + kt * BK;
    unsigned short* dstb = sB + (size_t)(s & 1) * SB_ELEMS;
#pragma unroll
    for (int j = 0; j < 4; ++j) {
      int L = j * 512 + t;               // chunk id 0..2047
      int row = L >> 2;                  // B row (= C column) 0..511
      int c = L & 3;                     // 16B chunk within 64B row
      gll16(src + (size_t)row * D_DIM + c * 8,
            dstb + (size_t)(j * 512 + w * 64) * 8);
    }
  };

  // x2 for this wave's rows (from LDS now)
  float4 x2v[4];
#pragma unroll
  for (int mi = 0; mi < 4; ++mi)
    x2v[mi] = *(const float4*)&sX[wm * 64 + mi * 16 + lhi * 4];

  stageB(0);
  __syncthreads();    // barrier drains vmcnt(0): B(step 0) ready

  for (int cg = 0; cg < 4; ++cg) {
    const int cgi = cg * 8 + bx;

    f32x4 acc[4][8];
#pragma unroll
    for (int mi = 0; mi < 4; ++mi)
#pragma unroll
      for (int ni = 0; ni < 8; ++ni)
        acc[mi][ni] = (f32x4){0.f, 0.f, 0.f, 0.f};

    for (int kt = 0; kt < 8; ++kt) {
      const int s = cg * 8 + kt;
      if (s + 1 < 32) stageB(s + 1);     // prefetch into other buffer

      // A fragments: logical chunk kt*4+lhi, physical = swizzled
      f16x8 af[4];
#pragma unroll
      for (int mi = 0; mi < 4; ++mi) {
        int arow = wm * 64 + mi * 16 + lrow;
        int lc   = kt * 4 + lhi;
        int pc   = (lc & 24) | ((lc & 7) ^ (lrow & 7));
        af[mi] = *(const f16x8*)(sA + (size_t)arow * 256 + pc * 8);
      }

      const unsigned short* bbuf = sB + (size_t)(s & 1) * SB_ELEMS;
#pragma unroll
      for (int half = 0; half < 2; ++half) {
        f16x8 bf[4];
#pragma unroll
        for (int nj = 0; nj < 4; ++nj) {
          int brow = wn * 128 + (half * 4 + nj) * 16 + lrow;
          bf[nj] = *(const f16x8*)(bbuf + (size_t)brow * BK + lhi * 8);
        }
#pragma unroll
        for (int mi = 0; mi < 4; ++mi)
#pragma unroll
          for (int nj = 0; nj < 4; ++nj)
            acc[mi][half * 4 + nj] =
                __builtin_amdgcn_mfma_f32_16x16x32_f16(af[mi], bf[nj],
                                                       acc[mi][half * 4 + nj], 0, 0, 0);
      }
      __syncthreads();   // prefetch drained; buffer swap safe
    }

    // ---- epilogue: dist + row partial sums into this wave's rowacc slice ----
    float yv[8];
#pragma unroll
    for (int ni = 0; ni < 8; ++ni)
      yv[ni] = y2[cgi * CGC + wn * 128 + ni * 16 + lrow];

#pragma unroll
    for (int mi = 0; mi < 4; ++mi) {
      float xr[4] = {x2v[mi].x, x2v[mi].y, x2v[mi].z, x2v[mi].w};
#pragma unroll
      for (int rr = 0; rr < 4; ++rr) {
        float ssum = 0.f;
#pragma unroll
        for (int ni = 0; ni < 8; ++ni) {
          float d2 = xr[rr] + yv[ni] - 2.0f * acc[mi][ni][rr];
          d2 = fmaxf(d2, 0.0f);
          ssum += __builtin_amdgcn_sqrtf(d2 + EPSF);
        }
        ssum += __shfl_xor(ssum, 1, 64);
        ssum += __shfl_xor(ssum, 2, 64);
        ssum += __shfl_xor(ssum, 4, 64);
        ssum += __shfl_xor(ssum, 8, 64);
        if (lrow == 0)
          rowacc[wn][wm * 64 + mi * 16 + lhi * 4 + rr] += ssum;  // wave-private slice
      }
    }
  }

  __syncthreads();
  if (t < 128)
    partial[(size_t)bx * N_IDE + by * 128 + t] =
        rowacc[0][t] + rowacc[1][t] + rowacc[2][t] + rowacc[3][t];
}

// ---- Kernel 2: loss = sum_{i,j} sqrt(((d_i-d_j))^2 + eps), d from partials ----
__global__ __launch_bounds__(256) void k_loss(const float* __restrict__ partial,
                                              float* __restrict__ out) {
  __shared__ float sd[N_IDE];
  __shared__ float wsum[4];
  int t = threadIdx.x;
  for (int k = t; k < N_IDE; k += 256) {
    float s = 0.f;
#pragma unroll
    for (int b = 0; b < 8; ++b) s += partial[(size_t)b * N_IDE + k];
    sd[k] = s;
  }
  __syncthreads();
  int tid = blockIdx.x * 256 + t;   // 65536 threads: 16 per i
  int i   = tid >> 4;
  int jl  = tid & 15;
  float di = sd[i];
  float s  = 0.f;
  for (int k = 0; k < 256; ++k) {
    float diff = (di - sd[jl + k * 16]) * INV_M;
    s += __builtin_amdgcn_sqrtf(diff * diff + EPSF);
  }
#pragma unroll
  for (int m = 1; m <= 32; m <<= 1) s += __shfl_xor(s, m, 64);
  if ((t & 63) == 0) wsum[t >> 6] = s;
  __syncthreads();
  if (t == 0) atomicAdd(out, wsum[0] + wsum[1] + wsum[2] + wsum[3]);
}

extern "C" void kernel_launch(void* const* d_in, const int* in_sizes, int n_in,
                              void* d_out, int out_size, void* d_ws, size_t ws_size,
                              hipStream_t stream) {
  (void)in_sizes; (void)n_in; (void)out_size; (void)ws_size;
  const float* ide = (const float*)d_in[0];
  const float* u   = (const float*)d_in[1];
  float* out = (float*)d_out;

  char* ws = (char*)d_ws;
  size_t off = 0;
  unsigned short* Bh = (unsigned short*)(ws + off); off += (size_t)M_U * D_DIM * 2;    // 8 MB
  float* y2      = (float*)(ws + off); off += (size_t)M_U * 4;
  float* partial = (float*)(ws + off); off += (size_t)8 * N_IDE * 4;                   // 128 KB
  unsigned int* cnt = (unsigned int*)(ws + off); off += 64;

  hipMemsetAsync(cnt, 0, sizeof(unsigned int), stream);   // ~free (r7 evidence)
  k_main<<<dim3(8, 32), 512, 0, stream>>>(ide, u, Bh, y2, partial, cnt, out);
  k_loss<<<256, 256, 0, stream>>>(partial, out);
}

// Round 11
// 165.917 us; speedup vs baseline: 1.0913x; 1.0913x over previous
//
#include <hip/hip_runtime.h>
#include <hip/hip_bf16.h>
#include <cstdint>

#define N_IDE 4096
#define M_U   16384
#define D_DIM 256
#define EPSF  1e-12f
#define INV_M (1.0f / 16384.0f)

#define CGC   512                 // columns per column-group tile
#define BK    32                  // K per step
#define SB_ELEMS (CGC * BK)       // 16384 f16 = 32 KB

typedef _Float16 f16x8 __attribute__((ext_vector_type(8)));
typedef float    f32x4 __attribute__((ext_vector_type(4)));

// ---- async global->LDS 16B copy. LDS dest = wave-uniform base + lane*16. ----
__device__ __forceinline__ void gll16(const void* g, void* l) {
  __builtin_amdgcn_global_load_lds(
      (const __attribute__((address_space(1))) void*)(uintptr_t)g,
      (__attribute__((address_space(3))) void*)(uint32_t)(uintptr_t)l,
      16, 0, 0);
}

__device__ __forceinline__ unsigned short f2h_bits(float f) {
  _Float16 h = (_Float16)f;
  return __builtin_bit_cast(unsigned short, h);
}

// ---- Kernel 1: fp32 -> f16 convert + row squared-norms (r7 verbatim) ----
__global__ __launch_bounds__(256) void k_conv(const float* __restrict__ ide,
                                              const float* __restrict__ u,
                                              unsigned short* __restrict__ Ah,
                                              unsigned short* __restrict__ Bh,
                                              float* __restrict__ x2,
                                              float* __restrict__ y2,
                                              float* __restrict__ out) {
  if (blockIdx.x == 0 && threadIdx.x == 0) out[0] = 0.f;
  int gw = (blockIdx.x * 256 + threadIdx.x) >> 6;
  int l  = threadIdx.x & 63;
  const float4* src;
  ushort4* dst;
  float* nrm;
  if (gw < N_IDE) {
    src = (const float4*)(ide + (size_t)gw * D_DIM);
    dst = (ushort4*)(Ah + (size_t)gw * D_DIM);
    nrm = x2 + gw;
  } else {
    int r = gw - N_IDE;
    src = (const float4*)(u + (size_t)r * D_DIM);
    dst = (ushort4*)(Bh + (size_t)r * D_DIM);
    nrm = y2 + r;
  }
  float4 v = src[l];
  float s = v.x * v.x + v.y * v.y + v.z * v.z + v.w * v.w;
  ushort4 o;
  o.x = f2h_bits(v.x); o.y = f2h_bits(v.y);
  o.z = f2h_bits(v.z); o.w = f2h_bits(v.w);
  dst[l] = o;
#pragma unroll
  for (int m = 1; m <= 32; m <<= 1) s += __shfl_xor(s, m, 64);
  if (l == 0) *nrm = s;
}

// ---- Kernel 2: r7 GEMM (verbatim) + END-fused loss via device handshake ----
// GEMM body bit-identical to the 51.7us r7 kernel. After the partial store:
// threadfence -> syncthreads -> release-add(cnt); t0 spins until cnt==256
// (all 256 blocks co-resident at 1 block/CU -- proven safe in r10); then the
// 256 blocks run the old k_loss body in-place (512 thr -> 32 lanes per row).
// r10's lesson applied: the handshake sits AFTER the 12MB staging loop, so
// the fence/acquire cache flushes only tax a 16KB-read loss phase, not 32
// barrier-lockstep staging rounds. Deletes one ~18-20us launch boundary.
__global__ __launch_bounds__(512, 2) void k_gemm(const unsigned short* __restrict__ Ah,
                                                 const unsigned short* __restrict__ Bh,
                                                 const float* __restrict__ x2,
                                                 const float* __restrict__ y2,
                                                 float* __restrict__ partial,
                                                 unsigned int* __restrict__ cnt,
                                                 float* __restrict__ out) {
  __shared__ __align__(16) unsigned short sA[128 * 256];      // 64 KB
  __shared__ __align__(16) unsigned short sB[2 * SB_ELEMS];   // 64 KB
  __shared__ float rowacc[4][128];                            // per-wn slices

  const int t    = threadIdx.x;
  const int w    = t >> 6;
  const int l    = t & 63;
  const int wm   = w >> 2, wn = w & 3;   // 2x4 wave grid; wave tile 64x128
  const int lrow = l & 15;
  const int lhi  = l >> 4;
  const int bx   = blockIdx.x;           // 0..7
  const int by   = blockIdx.y;           // 0..31
  const int blk  = by * 8 + bx;          // 0..255

  rowacc[t >> 7][t & 127] = 0.f;         // 512 threads cover 4x128 exactly

  // ---- stage A (128 rows x 256 K), XOR-swizzled in 16B chunks ----
#pragma unroll
  for (int i = 0; i < 8; ++i) {
    int L = i * 512 + t;                 // chunk id 0..4095
    int row = L >> 5;
    int p = L & 31;
    int c = (p & 24) | ((p & 7) ^ (row & 7));
    gll16(Ah + (size_t)(by * 128 + row) * D_DIM + c * 8,
          sA + (size_t)(i * 512 + w * 64) * 8);
  }

  // ---- B tile stage: flat step s -> buf s&1 (natural layout, no swizzle) ----
  auto stageB = [&](int s) {
    const int cgi = (s >> 3) * 8 + bx;   // column-group 0..31
    const int kt  = s & 7;
    const unsigned short* src = Bh + (size_t)cgi * CGC * D_DIM + kt * BK;
    unsigned short* dstb = sB + (size_t)(s & 1) * SB_ELEMS;
#pragma unroll
    for (int j = 0; j < 4; ++j) {
      int L = j * 512 + t;               // chunk id 0..2047
      int row = L >> 2;                  // B row (= C column) 0..511
      int c = L & 3;                     // 16B chunk within 64B row
      gll16(src + (size_t)row * D_DIM + c * 8,
            dstb + (size_t)(j * 512 + w * 64) * 8);
    }
  };

  // x2 for this wave's rows, loaded once (rr 0..3 contiguous -> float4)
  float4 x2v[4];
#pragma unroll
  for (int mi = 0; mi < 4; ++mi)
    x2v[mi] = *(const float4*)&x2[by * 128 + wm * 64 + mi * 16 + lhi * 4];

  stageB(0);
  __syncthreads();    // barrier drains vmcnt(0): A + B(step 0) ready

  for (int cg = 0; cg < 4; ++cg) {
    const int cgi = cg * 8 + bx;

    f32x4 acc[4][8];
#pragma unroll
    for (int mi = 0; mi < 4; ++mi)
#pragma unroll
      for (int ni = 0; ni < 8; ++ni)
        acc[mi][ni] = (f32x4){0.f, 0.f, 0.f, 0.f};

    for (int kt = 0; kt < 8; ++kt) {
      const int s = cg * 8 + kt;
      if (s + 1 < 32) stageB(s + 1);     // prefetch into other buffer

      // A fragments: logical chunk kt*4+lhi, physical = swizzled
      f16x8 af[4];
#pragma unroll
      for (int mi = 0; mi < 4; ++mi) {
        int arow = wm * 64 + mi * 16 + lrow;
        int lc   = kt * 4 + lhi;
        int pc   = (lc & 24) | ((lc & 7) ^ (lrow & 7));
        af[mi] = *(const f16x8*)(sA + (size_t)arow * 256 + pc * 8);
      }

      const unsigned short* bbuf = sB + (size_t)(s & 1) * SB_ELEMS;
#pragma unroll
      for (int half = 0; half < 2; ++half) {
        f16x8 bf[4];
#pragma unroll
        for (int nj = 0; nj < 4; ++nj) {
          int brow = wn * 128 + (half * 4 + nj) * 16 + lrow;
          bf[nj] = *(const f16x8*)(bbuf + (size_t)brow * BK + lhi * 8);
        }
#pragma unroll
        for (int mi = 0; mi < 4; ++mi)
#pragma unroll
          for (int nj = 0; nj < 4; ++nj)
            acc[mi][half * 4 + nj] =
                __builtin_amdgcn_mfma_f32_16x16x32_f16(af[mi], bf[nj],
                                                       acc[mi][half * 4 + nj], 0, 0, 0);
      }
      __syncthreads();   // prefetch drained; buffer swap safe
    }

    // ---- epilogue: dist + row partial sums into this wave's rowacc slice ----
    float yv[8];
#pragma unroll
    for (int ni = 0; ni < 8; ++ni)
      yv[ni] = y2[cgi * CGC + wn * 128 + ni * 16 + lrow];

#pragma unroll
    for (int mi = 0; mi < 4; ++mi) {
      float xr[4] = {x2v[mi].x, x2v[mi].y, x2v[mi].z, x2v[mi].w};
#pragma unroll
      for (int rr = 0; rr < 4; ++rr) {
        float ssum = 0.f;
#pragma unroll
        for (int ni = 0; ni < 8; ++ni) {
          float d2 = xr[rr] + yv[ni] - 2.0f * acc[mi][ni][rr];
          d2 = fmaxf(d2, 0.0f);
          ssum += __builtin_amdgcn_sqrtf(d2 + EPSF);
        }
        ssum += __shfl_xor(ssum, 1, 64);
        ssum += __shfl_xor(ssum, 2, 64);
        ssum += __shfl_xor(ssum, 4, 64);
        ssum += __shfl_xor(ssum, 8, 64);
        if (lrow == 0)
          rowacc[wn][wm * 64 + mi * 16 + lhi * 4 + rr] += ssum;  // wave-private slice
      }
    }
  }

  __syncthreads();
  if (t < 128)
    partial[(size_t)bx * N_IDE + by * 128 + t] =
        rowacc[0][t] + rowacc[1][t] + rowacc[2][t] + rowacc[3][t];

  // ================= end-handshake + fused loss =================
  __threadfence();                       // publish partial (device scope)
  __syncthreads();                       // all storers' fences complete
  if (t == 0) {
    __hip_atomic_fetch_add(cnt, 1u, __ATOMIC_RELEASE, __HIP_MEMORY_SCOPE_AGENT);
    while (__hip_atomic_load(cnt, __ATOMIC_ACQUIRE, __HIP_MEMORY_SCOPE_AGENT) < 256u)
      __builtin_amdgcn_s_sleep(4);
  }
  __syncthreads();                       // all partials visible to this block

  // old k_loss body, 512 threads: sd in LDS (alias sA), 32 lanes per row i
  float* sd = (float*)sA;                // 16 KB needed, sA is 64 KB
  for (int k = t; k < N_IDE; k += 512) {
    float s = 0.f;
#pragma unroll
    for (int b = 0; b < 8; ++b) s += partial[(size_t)b * N_IDE + k];
    sd[k] = s;                           // identical FP order every block
  }
  __syncthreads();
  {
    const int gtid = blk * 512 + t;      // 131072 threads: 32 per row i
    const int i  = gtid >> 5;
    const int jl = gtid & 31;
    const float di = sd[i];
    float s = 0.f;
    for (int k = 0; k < 128; ++k) {
      float diff = (di - sd[jl + k * 32]) * INV_M;
      s += __builtin_amdgcn_sqrtf(diff * diff + EPSF);
    }
#pragma unroll
    for (int m = 1; m <= 32; m <<= 1) s += __shfl_xor(s, m, 64);
    if (l == 0) rowacc[0][w] = s;        // reuse rowacc as wsum[8]
    __syncthreads();
    if (t == 0) {
      float tot = 0.f;
#pragma unroll
      for (int q = 0; q < 8; ++q) tot += rowacc[0][q];
      atomicAdd(out, tot);
    }
  }
}

extern "C" void kernel_launch(void* const* d_in, const int* in_sizes, int n_in,
                              void* d_out, int out_size, void* d_ws, size_t ws_size,
                              hipStream_t stream) {
  (void)in_sizes; (void)n_in; (void)out_size; (void)ws_size;
  const float* ide = (const float*)d_in[0];
  const float* u   = (const float*)d_in[1];
  float* out = (float*)d_out;

  char* ws = (char*)d_ws;
  size_t off = 0;
  unsigned short* Ah = (unsigned short*)(ws + off); off += (size_t)N_IDE * D_DIM * 2;  // 2 MB
  unsigned short* Bh = (unsigned short*)(ws + off); off += (size_t)M_U  * D_DIM * 2;   // 8 MB
  float* x2      = (float*)(ws + off); off += (size_t)N_IDE * 4;
  float* y2      = (float*)(ws + off); off += (size_t)M_U * 4;
  float* partial = (float*)(ws + off); off += (size_t)8 * N_IDE * 4;                   // 128 KB
  unsigned int* cnt = (unsigned int*)(ws + off); off += 64;

  hipMemsetAsync(cnt, 0, sizeof(unsigned int), stream);   // ~free (r7 evidence)
  k_conv<<<(N_IDE + M_U) / 4, 256, 0, stream>>>(ide, u, Ah, Bh, x2, y2, out);
  k_gemm<<<dim3(8, 32), 512, 0, stream>>>(Ah, Bh, x2, y2, partial, cnt, out);
}

// Round 12
// 127.318 us; speedup vs baseline: 1.4221x; 1.3032x over previous
//
#include <hip/hip_runtime.h>
#include <hip/hip_bf16.h>
#include <cstdint>

#define N_IDE 4096
#define M_U   16384
#define D_DIM 256
#define EPSF  1e-12f
#define INV_M (1.0f / 16384.0f)

#define CGC   512                 // columns per column-group tile
#define BK    32                  // K per step
#define SB_ELEMS (CGC * BK)       // 16384 f16 = 32 KB

typedef _Float16 f16x8 __attribute__((ext_vector_type(8)));
typedef float    f32x4 __attribute__((ext_vector_type(4)));

// ---- async global->LDS 16B copy. LDS dest = wave-uniform base + lane*16. ----
__device__ __forceinline__ void gll16(const void* g, void* l) {
  __builtin_amdgcn_global_load_lds(
      (const __attribute__((address_space(1))) void*)(uintptr_t)g,
      (__attribute__((address_space(3))) void*)(uint32_t)(uintptr_t)l,
      16, 0, 0);
}

__device__ __forceinline__ unsigned short f2h_bits(float f) {
  _Float16 h = (_Float16)f;
  return __builtin_bit_cast(unsigned short, h);
}

// ---- Kernel 1: fp32 -> f16 convert + row squared-norms (one wave per row) ----
__global__ __launch_bounds__(256) void k_conv(const float* __restrict__ ide,
                                              const float* __restrict__ u,
                                              unsigned short* __restrict__ Ah,
                                              unsigned short* __restrict__ Bh,
                                              float* __restrict__ x2,
                                              float* __restrict__ y2,
                                              float* __restrict__ out) {
  if (blockIdx.x == 0 && threadIdx.x == 0) out[0] = 0.f;   // replaces memset launch
  int gw = (blockIdx.x * 256 + threadIdx.x) >> 6;
  int l  = threadIdx.x & 63;
  const float4* src;
  ushort4* dst;
  float* nrm;
  if (gw < N_IDE) {
    src = (const float4*)(ide + (size_t)gw * D_DIM);
    dst = (ushort4*)(Ah + (size_t)gw * D_DIM);
    nrm = x2 + gw;
  } else {
    int r = gw - N_IDE;
    src = (const float4*)(u + (size_t)r * D_DIM);
    dst = (ushort4*)(Bh + (size_t)r * D_DIM);
    nrm = y2 + r;
  }
  float4 v = src[l];
  float s = v.x * v.x + v.y * v.y + v.z * v.z + v.w * v.w;
  ushort4 o;
  o.x = f2h_bits(v.x); o.y = f2h_bits(v.y);
  o.z = f2h_bits(v.z); o.w = f2h_bits(v.w);
  dst[l] = o;
#pragma unroll
  for (int m = 1; m <= 32; m <<= 1) s += __shfl_xor(s, m, 64);
  if (l == 0) *nrm = s;
}

// ---- Kernel 2: persistent-A MFMA GEMM, 512 threads (8 waves, 2/SIMD) ----
// grid (8, 32): by = 128-row group; bx picks 4 of 32 column-groups (512 cols).
// LDS: A 128x256 f16 (64KB, swizzled, staged once)
//    + B double-buffer 2 x (512 cols x 32 K) f16 (2x32KB, natural layout)
// Steps: s = cg*8 + kt, cg in 0..3, kt in 0..7. One-step-ahead B prefetch.
// Session-final notes (11 rounds of evidence):
//  * 51.7us = 665 GFLOP/s = the 2-phase structural ceiling (m233). Seven
//    structural variants (counted-vmcnt, barrier-free L2-direct, 8-phase
//    reads-first, 8-phase MFMA-first, 256-thread occupancy port, 2 swizzle
//    variants) all measured >= this kernel.
//  * B bank conflicts (3.15M cyc) are fully hidden under the barrier drain:
//    fixing them (r9) removed the counter but cost +2us of staging math.
//  * In-kernel cross-block sync (grid.sync / atomic handshake) costs
//    ~55-65us on gfx950 (per-XCD L2 writeback+invalidate) -- 3x a kernel
//    boundary. Launch-count reduction is NOT a lever (fixed ~55us harness
//    overhead, independent of launch count).
__global__ __launch_bounds__(512, 2) void k_gemm(const unsigned short* __restrict__ Ah,
                                                 const unsigned short* __restrict__ Bh,
                                                 const float* __restrict__ x2,
                                                 const float* __restrict__ y2,
                                                 float* __restrict__ partial) {
  __shared__ __align__(16) unsigned short sA[128 * 256];      // 64 KB
  __shared__ __align__(16) unsigned short sB[2 * SB_ELEMS];   // 64 KB
  __shared__ float rowacc[4][128];                            // per-wn slices

  const int t    = threadIdx.x;
  const int w    = t >> 6;
  const int l    = t & 63;
  const int wm   = w >> 2, wn = w & 3;   // 2x4 wave grid; wave tile 64x128
  const int lrow = l & 15;
  const int lhi  = l >> 4;
  const int bx   = blockIdx.x;           // 0..7
  const int by   = blockIdx.y;           // 0..31

  rowacc[t >> 7][t & 127] = 0.f;         // 512 threads cover 4x128 exactly

  // ---- stage A (128 rows x 256 K), XOR-swizzled in 16B chunks ----
#pragma unroll
  for (int i = 0; i < 8; ++i) {
    int L = i * 512 + t;                 // chunk id 0..4095
    int row = L >> 5;
    int p = L & 31;
    int c = (p & 24) | ((p & 7) ^ (row & 7));
    gll16(Ah + (size_t)(by * 128 + row) * D_DIM + c * 8,
          sA + (size_t)(i * 512 + w * 64) * 8);
  }

  // ---- B tile stage: flat step s -> buf s&1 (natural layout, no swizzle) ----
  auto stageB = [&](int s) {
    const int cgi = (s >> 3) * 8 + bx;   // column-group 0..31
    const int kt  = s & 7;
    const unsigned short* src = Bh + (size_t)cgi * CGC * D_DIM + kt * BK;
    unsigned short* dstb = sB + (size_t)(s & 1) * SB_ELEMS;
#pragma unroll
    for (int j = 0; j < 4; ++j) {
      int L = j * 512 + t;               // chunk id 0..2047
      int row = L >> 2;                  // B row (= C column) 0..511
      int c = L & 3;                     // 16B chunk within 64B row
      gll16(src + (size_t)row * D_DIM + c * 8,
            dstb + (size_t)(j * 512 + w * 64) * 8);
    }
  };

  // x2 for this wave's rows, loaded once (rr 0..3 contiguous -> float4)
  float4 x2v[4];
#pragma unroll
  for (int mi = 0; mi < 4; ++mi)
    x2v[mi] = *(const float4*)&x2[by * 128 + wm * 64 + mi * 16 + lhi * 4];

  stageB(0);
  __syncthreads();    // barrier drains vmcnt(0): A + B(step 0) ready

  for (int cg = 0; cg < 4; ++cg) {
    const int cgi = cg * 8 + bx;

    f32x4 acc[4][8];
#pragma unroll
    for (int mi = 0; mi < 4; ++mi)
#pragma unroll
      for (int ni = 0; ni < 8; ++ni)
        acc[mi][ni] = (f32x4){0.f, 0.f, 0.f, 0.f};

    for (int kt = 0; kt < 8; ++kt) {
      const int s = cg * 8 + kt;
      if (s + 1 < 32) stageB(s + 1);     // prefetch into other buffer

      // A fragments: logical chunk kt*4+lhi, physical = swizzled
      f16x8 af[4];
#pragma unroll
      for (int mi = 0; mi < 4; ++mi) {
        int arow = wm * 64 + mi * 16 + lrow;
        int lc   = kt * 4 + lhi;
        int pc   = (lc & 24) | ((lc & 7) ^ (lrow & 7));
        af[mi] = *(const f16x8*)(sA + (size_t)arow * 256 + pc * 8);
      }

      const unsigned short* bbuf = sB + (size_t)(s & 1) * SB_ELEMS;
#pragma unroll
      for (int half = 0; half < 2; ++half) {
        f16x8 bf[4];
#pragma unroll
        for (int nj = 0; nj < 4; ++nj) {
          int brow = wn * 128 + (half * 4 + nj) * 16 + lrow;
          bf[nj] = *(const f16x8*)(bbuf + (size_t)brow * BK + lhi * 8);
        }
#pragma unroll
        for (int mi = 0; mi < 4; ++mi)
#pragma unroll
          for (int nj = 0; nj < 4; ++nj)
            acc[mi][half * 4 + nj] =
                __builtin_amdgcn_mfma_f32_16x16x32_f16(af[mi], bf[nj],
                                                       acc[mi][half * 4 + nj], 0, 0, 0);
      }
      __syncthreads();   // prefetch drained; buffer swap safe
    }

    // ---- epilogue: dist + row partial sums into this wave's rowacc slice ----
    float yv[8];
#pragma unroll
    for (int ni = 0; ni < 8; ++ni)
      yv[ni] = y2[cgi * CGC + wn * 128 + ni * 16 + lrow];

#pragma unroll
    for (int mi = 0; mi < 4; ++mi) {
      float xr[4] = {x2v[mi].x, x2v[mi].y, x2v[mi].z, x2v[mi].w};
#pragma unroll
      for (int rr = 0; rr < 4; ++rr) {
        float ssum = 0.f;
#pragma unroll
        for (int ni = 0; ni < 8; ++ni) {
          float d2 = xr[rr] + yv[ni] - 2.0f * acc[mi][ni][rr];
          d2 = fmaxf(d2, 0.0f);
          ssum += __builtin_amdgcn_sqrtf(d2 + EPSF);
        }
        ssum += __shfl_xor(ssum, 1, 64);
        ssum += __shfl_xor(ssum, 2, 64);
        ssum += __shfl_xor(ssum, 4, 64);
        ssum += __shfl_xor(ssum, 8, 64);
        if (lrow == 0)
          rowacc[wn][wm * 64 + mi * 16 + lhi * 4 + rr] += ssum;  // wave-private slice
      }
    }
  }

  __syncthreads();
  if (t < 128)
    partial[(size_t)bx * N_IDE + by * 128 + t] =
        rowacc[0][t] + rowacc[1][t] + rowacc[2][t] + rowacc[3][t];
}

// ---- Kernel 3: loss = sum_{i,j} sqrt(((d_i-d_j))^2 + eps), d from partials ----
__global__ __launch_bounds__(256) void k_loss(const float* __restrict__ partial,
                                              float* __restrict__ out) {
  __shared__ float sd[N_IDE];
  __shared__ float wsum[4];
  int t = threadIdx.x;
  for (int k = t; k < N_IDE; k += 256) {
    float s = 0.f;
#pragma unroll
    for (int b = 0; b < 8; ++b) s += partial[(size_t)b * N_IDE + k];
    sd[k] = s;
  }
  __syncthreads();
  int tid = blockIdx.x * 256 + t;   // 65536 threads: 16 per i
  int i   = tid >> 4;
  int jl  = tid & 15;
  float di = sd[i];
  float s  = 0.f;
  for (int k = 0; k < 256; ++k) {
    float diff = (di - sd[jl + k * 16]) * INV_M;
    s += __builtin_amdgcn_sqrtf(diff * diff + EPSF);
  }
#pragma unroll
  for (int m = 1; m <= 32; m <<= 1) s += __shfl_xor(s, m, 64);
  if ((t & 63) == 0) wsum[t >> 6] = s;
  __syncthreads();
  if (t == 0) atomicAdd(out, wsum[0] + wsum[1] + wsum[2] + wsum[3]);
}

extern "C" void kernel_launch(void* const* d_in, const int* in_sizes, int n_in,
                              void* d_out, int out_size, void* d_ws, size_t ws_size,
                              hipStream_t stream) {
  (void)in_sizes; (void)n_in; (void)out_size; (void)ws_size;
  const float* ide = (const float*)d_in[0];
  const float* u   = (const float*)d_in[1];
  float* out = (float*)d_out;

  char* ws = (char*)d_ws;
  size_t off = 0;
  unsigned short* Ah = (unsigned short*)(ws + off); off += (size_t)N_IDE * D_DIM * 2;  // 2 MB
  unsigned short* Bh = (unsigned short*)(ws + off); off += (size_t)M_U  * D_DIM * 2;   // 8 MB
  float* x2      = (float*)(ws + off); off += (size_t)N_IDE * 4;
  float* y2      = (float*)(ws + off); off += (size_t)M_U * 4;
  float* partial = (float*)(ws + off); off += (size_t)8 * N_IDE * 4;                   // 128 KB

  k_conv<<<(N_IDE + M_U) / 4, 256, 0, stream>>>(ide, u, Ah, Bh, x2, y2, out);
  k_gemm<<<dim3(8, 32), 512, 0, stream>>>(Ah, Bh, x2, y2, partial);
  k_loss<<<256, 256, 0, stream>>>(partial, out);
}